// Round 5
// baseline (944.169 us; speedup 1.0000x reference)
//
#include <hip/hip_runtime.h>
#include <hip/hip_bf16.h>
#include <math.h>

#define NT 16     // nodes per block
#define RR 112    // real rows
#define RP 128    // padded rows (M)

typedef __attribute__((ext_vector_type(8))) short bf16x8;
typedef __attribute__((ext_vector_type(4))) float f32x4;

// ws layout (bf16 elements)
#define W1T_OFF 0
#define W1T_ELEMS (4*256*40)              // [v][o][i] i padded 7->40
#define W2T_OFF (W1T_OFF + W1T_ELEMS)
#define W2T_ELEMS (4*128*264)             // [v][h][o] o padded 256->264
#define A1T_OFF (W2T_OFF + W2T_ELEMS)
#define A1T_ELEMS (4*256*328)             // [v][h][i] i padded 320->328
#define WS_ELEMS (A1T_OFF + A1T_ELEMS)

__device__ __forceinline__ unsigned short f2b(float f) {
  union { float f; unsigned u; } x; x.f = f;
  unsigned r = x.u + 0x7fffu + ((x.u >> 16) & 1u);   // RNE
  return (unsigned short)(r >> 16);
}
__device__ __forceinline__ float b2f(unsigned short h) {
  union { unsigned u; float f; } x; x.u = ((unsigned)h) << 16; return x.f;
}

// ---------- prep: transpose+convert weights to bf16 in ws ----------
__global__ void scs_prep(const float* __restrict__ W1, const float* __restrict__ W2,
                         const float* __restrict__ A1, unsigned short* __restrict__ ws) {
  for (int e = blockIdx.x * 256 + threadIdx.x; e < WS_ELEMS; e += gridDim.x * 256) {
    unsigned short val;
    if (e < W2T_OFF) {                       // W1T[v][o][i]
      int r = e;            int v = r / (256*40); r %= (256*40);
      int o = r / 40, i = r % 40;
      val = (i < 7) ? f2b(W1[((size_t)v*7 + i)*256 + o]) : (unsigned short)0;
    } else if (e < A1T_OFF) {                // W2T[v][h][o]
      int r = e - W2T_OFF;  int v = r / (128*264); r %= (128*264);
      int h = r / 264, o = r % 264;
      val = (o < 256) ? f2b(W2[((size_t)v*256 + o)*128 + h]) : (unsigned short)0;
    } else {                                 // A1T[v][h][i]
      int r = e - A1T_OFF;  int v = r / (256*328); r %= (256*328);
      int h = r / 328, i = r % 328;
      val = (i < 320) ? f2b(A1[((size_t)v*320 + i)*256 + h]) : (unsigned short)0;
    }
    ws[e] = val;
  }
}

// ---------- main fused kernel ----------
// LDS pool layout (54272 B total -> exactly 3 blocks/CU: 3*54272 = 162816 <= 163840):
//   [0,35072)      phase<=1: featb[128][40]u16 | encA[16][200]u16 | h1buf[128][72]u16
//                  phase>=2: basis[128][136]u16 (34816 B) aliases all three
//   [35072,51712)  encpre f32 [16][260]
//   [51712,52224)  inv_s  f32 [16][8]
//   [52224,54272)  rowpart f32 [4][128]
__global__ __launch_bounds__(256, 3)
void scs_fused(const float* __restrict__ centers_g,   // N*3
               const float* __restrict__ enc_g,       // N*64
               const float* __restrict__ enc_n,       // N*128
               const float* __restrict__ nb_pos,      // N*6*3
               const float* __restrict__ normals_g,   // N*3
               const float* __restrict__ nb_norm,     // N*6*3
               const float* __restrict__ areas_g,     // N*1
               const float* __restrict__ nb_area,     // N*6
               const unsigned short* __restrict__ ws, // bf16 weights
               const float* __restrict__ b1,          // V*256
               const float* __restrict__ b2,          // V*128
               const float* __restrict__ Ab1,         // V*256
               const float* __restrict__ A2,          // V*256
               const float* __restrict__ Ab2,         // V
               float* __restrict__ out,               // N*4
               int Nn)
{
  const int v  = blockIdx.y;
  const int n0 = blockIdx.x * NT;
  const int t  = threadIdx.x;
  const int lane = t & 63;
  const int wv = t >> 6;       // wave 0..3
  const int lr = lane & 15;    // tile row/col lane id
  const int lk = lane >> 4;    // k-group 0..3

  __shared__ __align__(16) char pool[54272];
  unsigned short* featb  = (unsigned short*)(pool + 0);        // [128][40]
  unsigned short* encA   = (unsigned short*)(pool + 10240);    // [16][200]
  unsigned short* h1buf  = (unsigned short*)(pool + 16640);    // [128][72]
  unsigned short* basis  = (unsigned short*)(pool + 0);        // [128][136] (alias)
  float*          encpre = (float*)(pool + 35072);             // [16][260]
  float*          inv_s  = (float*)(pool + 51712);             // [16][8]
  float*          rowpart= (float*)(pool + 52224);             // [4][128]

  // ---------- Phase 0: featurize + encA fill ----------
  for (int e = t; e < NT * 192; e += 256) {
    int row = e / 192, c = e % 192;
    int n = n0 + row; if (n >= Nn) n = Nn - 1;
    float val = (c < 128) ? enc_n[(size_t)n * 128 + c] : enc_g[(size_t)n * 64 + (c - 128)];
    encA[row * 200 + c] = f2b(val);
  }
  if (t < RP) {
    float f[8];
    #pragma unroll
    for (int i = 0; i < 8; i++) f[i] = 0.f;
    const int r = t;
    if (r < RR) {
      const int j = r / 7, p = r % 7;
      const int n = n0 + j;
      if (n < Nn) {
        if (p == 0) {
          f[0] = centers_g[(size_t)n*3+0]; f[1] = centers_g[(size_t)n*3+1]; f[2] = centers_g[(size_t)n*3+2];
          f[3] = normals_g[(size_t)n*3+0]; f[4] = normals_g[(size_t)n*3+1]; f[5] = normals_g[(size_t)n*3+2];
          f[6] = logf(areas_g[n]) * 0.1f;
        } else {
          const int s = p - 1;
          const float* mp = nb_pos  + ((size_t)n*6 + s)*3;
          const float* mn = nb_norm + ((size_t)n*6 + s)*3;
          f[0] = mp[0] + 1e-6f; f[1] = mp[1] + 1e-6f; f[2] = mp[2] + 1e-6f;
          f[3] = mn[0] + 1e-6f; f[4] = mn[1] + 1e-6f; f[5] = mn[2] + 1e-6f;
          f[6] = logf(nb_area[(size_t)n*6 + s]) * 0.1f + 1e-6f;
        }
      }
    }
    unsigned* fb32 = reinterpret_cast<unsigned*>(featb);
    #pragma unroll
    for (int i = 0; i < 4; i++) {
      unsigned lo = f2b(f[2*i]), hi = f2b(f[2*i+1]);
      fb32[r * 20 + i] = lo | (hi << 16);
    }
    #pragma unroll
    for (int i = 4; i < 20; i++) fb32[r * 20 + i] = 0;
  }
  __syncthreads();

  // feat A-fragments -> registers
  bf16x8 ffrag[8];
  #pragma unroll
  for (int mt = 0; mt < 8; ++mt)
    ffrag[mt] = *(const bf16x8*)&featb[(mt*16 + lr)*40 + lk*8];

  // 1/dist (bf16 features, 7 dims)
  if (t < NT * 6) {
    const int j = t / 6, s = t % 6;
    float d2 = 0.f;
    #pragma unroll
    for (int i = 0; i < 7; i++) {
      const float d = b2f(featb[(j*7)*40 + i]) - b2f(featb[(j*7 + 1 + s)*40 + i]);
      d2 += d * d;
    }
    inv_s[j*8 + s] = 1.f / sqrtf(d2);
  }

  const unsigned short* w1t = ws + W1T_OFF + (size_t)v * 256 * 40;
  const unsigned short* w2t = ws + W2T_OFF + (size_t)v * 128 * 264;
  const unsigned short* a1t = ws + A1T_OFF + (size_t)v * 256 * 328;

  // ---------- Phase 0.5: enc GEMM (M=16, K=192, N=256 split by wave) ----------
  {
    f32x4 acc_e[4];
    #pragma unroll
    for (int nt = 0; nt < 4; ++nt) {
      const float ab = Ab1[v*256 + wv*64 + nt*16 + lr];
      acc_e[nt] = (f32x4){ab, ab, ab, ab};
    }
    #pragma unroll
    for (int ks = 0; ks < 6; ++ks) {
      const bf16x8 af = *(const bf16x8*)&encA[lr*200 + ks*32 + lk*8];
      #pragma unroll
      for (int nt = 0; nt < 4; ++nt) {
        const bf16x8 bf = *(const bf16x8*)(a1t + (size_t)(wv*64 + nt*16 + lr)*328 + 128 + ks*32 + lk*8);
        acc_e[nt] = __builtin_amdgcn_mfma_f32_16x16x32_bf16(af, bf, acc_e[nt], 0, 0, 0);
      }
    }
    #pragma unroll
    for (int nt = 0; nt < 4; ++nt)
      #pragma unroll
      for (int g = 0; g < 4; ++g)
        encpre[(lk*4 + g)*260 + wv*64 + nt*16 + lr] = acc_e[nt][g];
  }

  // ---------- Phase 1: chunk loop — H1 then BASIS accumulate ----------
  f32x4 acc_b[8][2];
  {
    #pragma unroll
    for (int nt = 0; nt < 2; ++nt) {
      const float bb = b2[v*128 + wv*32 + nt*16 + lr];
      #pragma unroll
      for (int mt = 0; mt < 8; ++mt) acc_b[mt][nt] = (f32x4){bb, bb, bb, bb};
    }
  }

  for (int ch = 0; ch < 4; ++ch) {
    // H1: wave computes o-tile [ch*64 + wv*16, +16) for all rows
    {
      const int obase = ch*64 + wv*16;
      const bf16x8 bfrag = *(const bf16x8*)(w1t + (size_t)(obase + lr)*40 + lk*8);
      const float b1c = b1[v*256 + obase + lr];
      #pragma unroll
      for (int mt = 0; mt < 8; ++mt) {
        f32x4 c = (f32x4){b1c, b1c, b1c, b1c};
        c = __builtin_amdgcn_mfma_f32_16x16x32_bf16(ffrag[mt], bfrag, c, 0, 0, 0);
        #pragma unroll
        for (int g = 0; g < 4; ++g)
          h1buf[(mt*16 + lk*4 + g)*72 + wv*16 + lr] = f2b(fmaxf(c[g], 0.f));
      }
    }
    __syncthreads();
    // BASIS accumulate: 2 ksteps, wave N strip = [wv*32, +32)
    #pragma unroll
    for (int ksl = 0; ksl < 2; ++ksl) {
      bf16x8 bf[2];
      #pragma unroll
      for (int nt = 0; nt < 2; ++nt)
        bf[nt] = *(const bf16x8*)(w2t + (size_t)(wv*32 + nt*16 + lr)*264 + ch*64 + ksl*32 + lk*8);
      #pragma unroll
      for (int mt = 0; mt < 8; ++mt) {
        const bf16x8 af = *(const bf16x8*)&h1buf[(mt*16 + lr)*72 + ksl*32 + lk*8];
        acc_b[mt][0] = __builtin_amdgcn_mfma_f32_16x16x32_bf16(af, bf[0], acc_b[mt][0], 0, 0, 0);
        acc_b[mt][1] = __builtin_amdgcn_mfma_f32_16x16x32_bf16(af, bf[1], acc_b[mt][1], 0, 0, 0);
      }
    }
    __syncthreads();
  }

  // ---------- Phase 2: write full basis (aliases featb/encA/h1buf — all dead) ----------
  #pragma unroll
  for (int mt = 0; mt < 8; ++mt)
    #pragma unroll
    for (int nt = 0; nt < 2; ++nt)
      #pragma unroll
      for (int g = 0; g < 4; ++g)
        basis[(mt*16 + lk*4 + g)*136 + wv*32 + nt*16 + lr] = f2b(acc_b[mt][nt][g]);
  __syncthreads();

  // ---------- Phase 3: H2 in two N-passes of 128 cols; fold relu·A2 per pass ----------
  float srow[8][4];
  #pragma unroll
  for (int mt = 0; mt < 8; ++mt)
    #pragma unroll
    for (int g = 0; g < 4; ++g) srow[mt][g] = 0.f;

  #pragma unroll
  for (int p = 0; p < 2; ++p) {
    f32x4 acc_h[8][2];
    #pragma unroll
    for (int mt = 0; mt < 8; ++mt) {
      acc_h[mt][0] = (f32x4){0.f, 0.f, 0.f, 0.f};
      acc_h[mt][1] = (f32x4){0.f, 0.f, 0.f, 0.f};
    }
    const int cbase = p*128 + wv*32;
    #pragma unroll
    for (int ks = 0; ks < 4; ++ks) {
      bf16x8 bfr[2];
      #pragma unroll
      for (int nt = 0; nt < 2; ++nt)
        bfr[nt] = *(const bf16x8*)(a1t + (size_t)(cbase + nt*16 + lr)*328 + ks*32 + lk*8);
      #pragma unroll
      for (int mt = 0; mt < 8; ++mt) {
        const bf16x8 af = *(const bf16x8*)&basis[(mt*16 + lr)*136 + ks*32 + lk*8];
        acc_h[mt][0] = __builtin_amdgcn_mfma_f32_16x16x32_bf16(af, bfr[0], acc_h[mt][0], 0, 0, 0);
        acc_h[mt][1] = __builtin_amdgcn_mfma_f32_16x16x32_bf16(af, bfr[1], acc_h[mt][1], 0, 0, 0);
      }
    }
    // fold pass partials: relu(acc + encpre) . A2
    float a2c[2];
    #pragma unroll
    for (int nt = 0; nt < 2; ++nt) a2c[nt] = A2[v*256 + cbase + nt*16 + lr];
    #pragma unroll
    for (int mt = 0; mt < 8; ++mt) {
      #pragma unroll
      for (int g = 0; g < 4; ++g) {
        const int row = mt*16 + lk*4 + g;
        int j = row / 7; if (j > NT-1) j = NT-1;
        #pragma unroll
        for (int nt = 0; nt < 2; ++nt) {
          const float h2 = acc_h[mt][nt][g] + encpre[j*260 + cbase + nt*16 + lr];
          srow[mt][g] += fmaxf(h2, 0.f) * a2c[nt];
        }
      }
    }
  }

  // ---------- Phase 4: reduce over the 16 lr lanes, stash per-wave row partials ----------
  #pragma unroll
  for (int mt = 0; mt < 8; ++mt) {
    #pragma unroll
    for (int g = 0; g < 4; ++g) {
      float s = srow[mt][g];
      s += __shfl_xor(s, 1); s += __shfl_xor(s, 2);
      s += __shfl_xor(s, 4); s += __shfl_xor(s, 8);
      if (lr == 0) rowpart[wv*RP + mt*16 + lk*4 + g] = s;
    }
  }
  __syncthreads();

  // ---------- Phase 5: combine + write ----------
  if (t < NT) {
    const int n = n0 + t;
    if (n < Nn) {
      const float ab2v = Ab2[v];
      float pt[7];
      #pragma unroll
      for (int p = 0; p < 7; ++p)
        pt[p] = rowpart[0*RP + t*7+p] + rowpart[1*RP + t*7+p]
              + rowpart[2*RP + t*7+p] + rowpart[3*RP + t*7+p] + ab2v;
      float snum = 0.f, sden = 0.f;
      #pragma unroll
      for (int s6 = 0; s6 < 6; ++s6) {
        const float iv = inv_s[t*8 + s6];
        snum += pt[1 + s6] * iv; sden += iv;
      }
      out[(size_t)n*4 + v] = 0.5f * pt[0] + 0.5f * snum / sden;
    }
  }
}

extern "C" void kernel_launch(void* const* d_in, const int* in_sizes, int n_in,
                              void* d_out, int out_size, void* d_ws, size_t ws_size,
                              hipStream_t stream) {
  (void)n_in; (void)out_size; (void)ws_size;
  const float* centers = (const float*)d_in[0];
  const float* encg    = (const float*)d_in[1];
  const float* encn    = (const float*)d_in[2];
  const float* nbpos   = (const float*)d_in[3];
  const float* normals = (const float*)d_in[4];
  const float* nbnorm  = (const float*)d_in[5];
  const float* areas   = (const float*)d_in[6];
  const float* nbarea  = (const float*)d_in[7];
  const float* W1  = (const float*)d_in[10];
  const float* b1  = (const float*)d_in[11];
  const float* W2  = (const float*)d_in[12];
  const float* b2  = (const float*)d_in[13];
  const float* A1  = (const float*)d_in[14];
  const float* Ab1 = (const float*)d_in[15];
  const float* A2  = (const float*)d_in[16];
  const float* Ab2 = (const float*)d_in[17];
  float* out = (float*)d_out;
  unsigned short* ws = (unsigned short*)d_ws;

  const int Nn = in_sizes[0] / 3;   // 30000

  hipLaunchKernelGGL(scs_prep, dim3(1024), dim3(256), 0, stream, W1, W2, A1, ws);

  dim3 grid((Nn + NT - 1) / NT, 4);
  hipLaunchKernelGGL(scs_fused, grid, dim3(256), 0, stream,
                     centers, encg, encn, nbpos, normals, nbnorm, areas, nbarea,
                     ws, b1, b2, Ab1, A2, Ab2, out, Nn);
}

// Round 6
// 463.096 us; speedup vs baseline: 2.0388x; 2.0388x over previous
//
#include <hip/hip_runtime.h>
#include <hip/hip_bf16.h>
#include <math.h>

#define NT 16     // nodes per block
#define RR 112    // real rows
#define RP 128    // padded rows (M)

typedef __attribute__((ext_vector_type(8))) short bf16x8;
typedef __attribute__((ext_vector_type(4))) float f32x4;

// ws layout (bf16 elements)
#define W1T_OFF 0
#define W1T_ELEMS (4*256*40)              // [v][o][i] i padded 7->40
#define W2T_OFF (W1T_OFF + W1T_ELEMS)
#define W2T_ELEMS (4*128*264)             // [v][h][o] o padded 256->264
#define A1T_OFF (W2T_OFF + W2T_ELEMS)
#define A1T_ELEMS (4*256*328)             // [v][h][i] i padded 320->328
#define WS_ELEMS (A1T_OFF + A1T_ELEMS)

__device__ __forceinline__ unsigned short f2b(float f) {
  union { float f; unsigned u; } x; x.f = f;
  unsigned r = x.u + 0x7fffu + ((x.u >> 16) & 1u);   // RNE
  return (unsigned short)(r >> 16);
}
__device__ __forceinline__ float b2f(unsigned short h) {
  union { unsigned u; float f; } x; x.u = ((unsigned)h) << 16; return x.f;
}

// ---------- prep: transpose+convert weights to bf16 in ws ----------
__global__ void scs_prep(const float* __restrict__ W1, const float* __restrict__ W2,
                         const float* __restrict__ A1, unsigned short* __restrict__ ws) {
  for (int e = blockIdx.x * 256 + threadIdx.x; e < WS_ELEMS; e += gridDim.x * 256) {
    unsigned short val;
    if (e < W2T_OFF) {                       // W1T[v][o][i]
      int r = e;            int v = r / (256*40); r %= (256*40);
      int o = r / 40, i = r % 40;
      val = (i < 7) ? f2b(W1[((size_t)v*7 + i)*256 + o]) : (unsigned short)0;
    } else if (e < A1T_OFF) {                // W2T[v][h][o]
      int r = e - W2T_OFF;  int v = r / (128*264); r %= (128*264);
      int h = r / 264, o = r % 264;
      val = (o < 256) ? f2b(W2[((size_t)v*256 + o)*128 + h]) : (unsigned short)0;
    } else {                                 // A1T[v][h][i]
      int r = e - A1T_OFF;  int v = r / (256*328); r %= (256*328);
      int h = r / 328, i = r % 328;
      val = (i < 320) ? f2b(A1[((size_t)v*320 + i)*256 + h]) : (unsigned short)0;
    }
    ws[e] = val;
  }
}

// ---------- main fused kernel ----------
// LDS pool layout (54272 B):
//   [0,35072)      phase<=1: featb[128][40]u16 | encA[16][200]u16 | h1buf[128][72]u16
//                  phase>=2: basis[128][136]u16 (34816 B) aliases all three
//   [35072,51712)  encpre f32 [16][260]
//   [51712,52224)  inv_s  f32 [16][8]
//   [52224,54272)  rowpart f32 [4][128]
// launch_bounds(256,2): cap 256 unified VGPR+AGPR. (256,3) caused ~84+84 split
// plus massive scratch spill (R4/R5: WRITE_SIZE 1.5-1.85 GB) — do not tighten.
__global__ __launch_bounds__(256, 2)
void scs_fused(const float* __restrict__ centers_g,   // N*3
               const float* __restrict__ enc_g,       // N*64
               const float* __restrict__ enc_n,       // N*128
               const float* __restrict__ nb_pos,      // N*6*3
               const float* __restrict__ normals_g,   // N*3
               const float* __restrict__ nb_norm,     // N*6*3
               const float* __restrict__ areas_g,     // N*1
               const float* __restrict__ nb_area,     // N*6
               const unsigned short* __restrict__ ws, // bf16 weights
               const float* __restrict__ b1,          // V*256
               const float* __restrict__ b2,          // V*128
               const float* __restrict__ Ab1,         // V*256
               const float* __restrict__ A2,          // V*256
               const float* __restrict__ Ab2,         // V
               float* __restrict__ out,               // N*4
               int Nn)
{
  const int v  = blockIdx.y;
  const int n0 = blockIdx.x * NT;
  const int t  = threadIdx.x;
  const int lane = t & 63;
  const int wv = t >> 6;       // wave 0..3
  const int lr = lane & 15;    // tile row/col lane id
  const int lk = lane >> 4;    // k-group 0..3

  __shared__ __align__(16) char pool[54272];
  unsigned short* featb  = (unsigned short*)(pool + 0);        // [128][40]
  unsigned short* encA   = (unsigned short*)(pool + 10240);    // [16][200]
  unsigned short* h1buf  = (unsigned short*)(pool + 16640);    // [128][72]
  unsigned short* basis  = (unsigned short*)(pool + 0);        // [128][136] (alias)
  float*          encpre = (float*)(pool + 35072);             // [16][260]
  float*          inv_s  = (float*)(pool + 51712);             // [16][8]
  float*          rowpart= (float*)(pool + 52224);             // [4][128]

  // ---------- Phase 0: featurize + encA fill ----------
  for (int e = t; e < NT * 192; e += 256) {
    int row = e / 192, c = e % 192;
    int n = n0 + row; if (n >= Nn) n = Nn - 1;
    float val = (c < 128) ? enc_n[(size_t)n * 128 + c] : enc_g[(size_t)n * 64 + (c - 128)];
    encA[row * 200 + c] = f2b(val);
  }
  if (t < RP) {
    float f[8];
    #pragma unroll
    for (int i = 0; i < 8; i++) f[i] = 0.f;
    const int r = t;
    if (r < RR) {
      const int j = r / 7, p = r % 7;
      const int n = n0 + j;
      if (n < Nn) {
        if (p == 0) {
          f[0] = centers_g[(size_t)n*3+0]; f[1] = centers_g[(size_t)n*3+1]; f[2] = centers_g[(size_t)n*3+2];
          f[3] = normals_g[(size_t)n*3+0]; f[4] = normals_g[(size_t)n*3+1]; f[5] = normals_g[(size_t)n*3+2];
          f[6] = logf(areas_g[n]) * 0.1f;
        } else {
          const int s = p - 1;
          const float* mp = nb_pos  + ((size_t)n*6 + s)*3;
          const float* mn = nb_norm + ((size_t)n*6 + s)*3;
          f[0] = mp[0] + 1e-6f; f[1] = mp[1] + 1e-6f; f[2] = mp[2] + 1e-6f;
          f[3] = mn[0] + 1e-6f; f[4] = mn[1] + 1e-6f; f[5] = mn[2] + 1e-6f;
          f[6] = logf(nb_area[(size_t)n*6 + s]) * 0.1f + 1e-6f;
        }
      }
    }
    unsigned* fb32 = reinterpret_cast<unsigned*>(featb);
    #pragma unroll
    for (int i = 0; i < 4; i++) {
      unsigned lo = f2b(f[2*i]), hi = f2b(f[2*i+1]);
      fb32[r * 20 + i] = lo | (hi << 16);
    }
    #pragma unroll
    for (int i = 4; i < 20; i++) fb32[r * 20 + i] = 0;
  }
  __syncthreads();

  // feat A-fragments -> registers
  bf16x8 ffrag[8];
  #pragma unroll
  for (int mt = 0; mt < 8; ++mt)
    ffrag[mt] = *(const bf16x8*)&featb[(mt*16 + lr)*40 + lk*8];

  // 1/dist (bf16 features, 7 dims)
  if (t < NT * 6) {
    const int j = t / 6, s = t % 6;
    float d2 = 0.f;
    #pragma unroll
    for (int i = 0; i < 7; i++) {
      const float d = b2f(featb[(j*7)*40 + i]) - b2f(featb[(j*7 + 1 + s)*40 + i]);
      d2 += d * d;
    }
    inv_s[j*8 + s] = 1.f / sqrtf(d2);
  }

  const unsigned short* w1t = ws + W1T_OFF + (size_t)v * 256 * 40;
  const unsigned short* w2t = ws + W2T_OFF + (size_t)v * 128 * 264;
  const unsigned short* a1t = ws + A1T_OFF + (size_t)v * 256 * 328;

  // ---------- Phase 0.5: enc GEMM (M=16, K=192, N=256 split by wave) ----------
  {
    f32x4 acc_e[4];
    #pragma unroll
    for (int nt = 0; nt < 4; ++nt) {
      const float ab = Ab1[v*256 + wv*64 + nt*16 + lr];
      acc_e[nt] = (f32x4){ab, ab, ab, ab};
    }
    #pragma unroll
    for (int ks = 0; ks < 6; ++ks) {
      const bf16x8 af = *(const bf16x8*)&encA[lr*200 + ks*32 + lk*8];
      #pragma unroll
      for (int nt = 0; nt < 4; ++nt) {
        const bf16x8 bf = *(const bf16x8*)(a1t + (size_t)(wv*64 + nt*16 + lr)*328 + 128 + ks*32 + lk*8);
        acc_e[nt] = __builtin_amdgcn_mfma_f32_16x16x32_bf16(af, bf, acc_e[nt], 0, 0, 0);
      }
    }
    #pragma unroll
    for (int nt = 0; nt < 4; ++nt)
      #pragma unroll
      for (int g = 0; g < 4; ++g)
        encpre[(lk*4 + g)*260 + wv*64 + nt*16 + lr] = acc_e[nt][g];
  }

  // ---------- Phase 1: chunk loop — H1 then BASIS accumulate ----------
  f32x4 acc_b[8][2];
  {
    #pragma unroll
    for (int nt = 0; nt < 2; ++nt) {
      const float bb = b2[v*128 + wv*32 + nt*16 + lr];
      #pragma unroll
      for (int mt = 0; mt < 8; ++mt) acc_b[mt][nt] = (f32x4){bb, bb, bb, bb};
    }
  }

  for (int ch = 0; ch < 4; ++ch) {
    // H1: wave computes o-tile [ch*64 + wv*16, +16) for all rows
    {
      const int obase = ch*64 + wv*16;
      const bf16x8 bfrag = *(const bf16x8*)(w1t + (size_t)(obase + lr)*40 + lk*8);
      const float b1c = b1[v*256 + obase + lr];
      #pragma unroll
      for (int mt = 0; mt < 8; ++mt) {
        f32x4 c = (f32x4){b1c, b1c, b1c, b1c};
        c = __builtin_amdgcn_mfma_f32_16x16x32_bf16(ffrag[mt], bfrag, c, 0, 0, 0);
        #pragma unroll
        for (int g = 0; g < 4; ++g)
          h1buf[(mt*16 + lk*4 + g)*72 + wv*16 + lr] = f2b(fmaxf(c[g], 0.f));
      }
    }
    __syncthreads();
    // BASIS accumulate: 2 ksteps, wave N strip = [wv*32, +32)
    #pragma unroll
    for (int ksl = 0; ksl < 2; ++ksl) {
      bf16x8 bf[2];
      #pragma unroll
      for (int nt = 0; nt < 2; ++nt)
        bf[nt] = *(const bf16x8*)(w2t + (size_t)(wv*32 + nt*16 + lr)*264 + ch*64 + ksl*32 + lk*8);
      #pragma unroll
      for (int mt = 0; mt < 8; ++mt) {
        const bf16x8 af = *(const bf16x8*)&h1buf[(mt*16 + lr)*72 + ksl*32 + lk*8];
        acc_b[mt][0] = __builtin_amdgcn_mfma_f32_16x16x32_bf16(af, bf[0], acc_b[mt][0], 0, 0, 0);
        acc_b[mt][1] = __builtin_amdgcn_mfma_f32_16x16x32_bf16(af, bf[1], acc_b[mt][1], 0, 0, 0);
      }
    }
    __syncthreads();
  }

  // ---------- Phase 2: write full basis (aliases featb/encA/h1buf — all dead) ----------
  #pragma unroll
  for (int mt = 0; mt < 8; ++mt)
    #pragma unroll
    for (int nt = 0; nt < 2; ++nt)
      #pragma unroll
      for (int g = 0; g < 4; ++g)
        basis[(mt*16 + lk*4 + g)*136 + wv*32 + nt*16 + lr] = f2b(acc_b[mt][nt][g]);
  __syncthreads();

  // ---------- Phase 3: H2 in two N-passes of 128 cols; fold relu·A2 per pass ----------
  float srow[8][4];
  #pragma unroll
  for (int mt = 0; mt < 8; ++mt)
    #pragma unroll
    for (int g = 0; g < 4; ++g) srow[mt][g] = 0.f;

  #pragma unroll
  for (int p = 0; p < 2; ++p) {
    f32x4 acc_h[8][2];
    #pragma unroll
    for (int mt = 0; mt < 8; ++mt) {
      acc_h[mt][0] = (f32x4){0.f, 0.f, 0.f, 0.f};
      acc_h[mt][1] = (f32x4){0.f, 0.f, 0.f, 0.f};
    }
    const int cbase = p*128 + wv*32;
    #pragma unroll
    for (int ks = 0; ks < 4; ++ks) {
      bf16x8 bfr[2];
      #pragma unroll
      for (int nt = 0; nt < 2; ++nt)
        bfr[nt] = *(const bf16x8*)(a1t + (size_t)(cbase + nt*16 + lr)*328 + ks*32 + lk*8);
      #pragma unroll
      for (int mt = 0; mt < 8; ++mt) {
        const bf16x8 af = *(const bf16x8*)&basis[(mt*16 + lr)*136 + ks*32 + lk*8];
        acc_h[mt][0] = __builtin_amdgcn_mfma_f32_16x16x32_bf16(af, bfr[0], acc_h[mt][0], 0, 0, 0);
        acc_h[mt][1] = __builtin_amdgcn_mfma_f32_16x16x32_bf16(af, bfr[1], acc_h[mt][1], 0, 0, 0);
      }
    }
    // fold pass partials: relu(acc + encpre) . A2
    float a2c[2];
    #pragma unroll
    for (int nt = 0; nt < 2; ++nt) a2c[nt] = A2[v*256 + cbase + nt*16 + lr];
    #pragma unroll
    for (int mt = 0; mt < 8; ++mt) {
      #pragma unroll
      for (int g = 0; g < 4; ++g) {
        const int row = mt*16 + lk*4 + g;
        int j = row / 7; if (j > NT-1) j = NT-1;
        #pragma unroll
        for (int nt = 0; nt < 2; ++nt) {
          const float h2 = acc_h[mt][nt][g] + encpre[j*260 + cbase + nt*16 + lr];
          srow[mt][g] += fmaxf(h2, 0.f) * a2c[nt];
        }
      }
    }
  }

  // ---------- Phase 4: reduce over the 16 lr lanes, stash per-wave row partials ----------
  #pragma unroll
  for (int mt = 0; mt < 8; ++mt) {
    #pragma unroll
    for (int g = 0; g < 4; ++g) {
      float s = srow[mt][g];
      s += __shfl_xor(s, 1); s += __shfl_xor(s, 2);
      s += __shfl_xor(s, 4); s += __shfl_xor(s, 8);
      if (lr == 0) rowpart[wv*RP + mt*16 + lk*4 + g] = s;
    }
  }
  __syncthreads();

  // ---------- Phase 5: combine + write ----------
  if (t < NT) {
    const int n = n0 + t;
    if (n < Nn) {
      const float ab2v = Ab2[v];
      float pt[7];
      #pragma unroll
      for (int p = 0; p < 7; ++p)
        pt[p] = rowpart[0*RP + t*7+p] + rowpart[1*RP + t*7+p]
              + rowpart[2*RP + t*7+p] + rowpart[3*RP + t*7+p] + ab2v;
      float snum = 0.f, sden = 0.f;
      #pragma unroll
      for (int s6 = 0; s6 < 6; ++s6) {
        const float iv = inv_s[t*8 + s6];
        snum += pt[1 + s6] * iv; sden += iv;
      }
      out[(size_t)n*4 + v] = 0.5f * pt[0] + 0.5f * snum / sden;
    }
  }
}

extern "C" void kernel_launch(void* const* d_in, const int* in_sizes, int n_in,
                              void* d_out, int out_size, void* d_ws, size_t ws_size,
                              hipStream_t stream) {
  (void)n_in; (void)out_size; (void)ws_size;
  const float* centers = (const float*)d_in[0];
  const float* encg    = (const float*)d_in[1];
  const float* encn    = (const float*)d_in[2];
  const float* nbpos   = (const float*)d_in[3];
  const float* normals = (const float*)d_in[4];
  const float* nbnorm  = (const float*)d_in[5];
  const float* areas   = (const float*)d_in[6];
  const float* nbarea  = (const float*)d_in[7];
  const float* W1  = (const float*)d_in[10];
  const float* b1  = (const float*)d_in[11];
  const float* W2  = (const float*)d_in[12];
  const float* b2  = (const float*)d_in[13];
  const float* A1  = (const float*)d_in[14];
  const float* Ab1 = (const float*)d_in[15];
  const float* A2  = (const float*)d_in[16];
  const float* Ab2 = (const float*)d_in[17];
  float* out = (float*)d_out;
  unsigned short* ws = (unsigned short*)d_ws;

  const int Nn = in_sizes[0] / 3;   // 30000

  hipLaunchKernelGGL(scs_prep, dim3(1024), dim3(256), 0, stream, W1, W2, A1, ws);

  dim3 grid((Nn + NT - 1) / NT, 4);
  hipLaunchKernelGGL(scs_fused, grid, dim3(256), 0, stream,
                     centers, encg, encn, nbpos, normals, nbnorm, areas, nbarea,
                     ws, b1, b2, Ab1, A2, Ab2, out, Nn);
}